// Round 6
// baseline (12167.331 us; speedup 1.0000x reference)
//
#include <hip/hip_runtime.h>
#include <math.h>

typedef float f4 __attribute__((ext_vector_type(4)));
typedef _Float16 h8 __attribute__((ext_vector_type(8)));

// ---------------- workspace layout (float offsets), total 32,210,944 f32 = 128.84 MB ----------------
// AX   : A@x all t [i][t*128+b*2+c]          6,144,000   (H1F fp32 aliases here at t=47)
// AHh/l: A@[H0|H1] split f16 [1024][8192]    2 x 4,194,304
// HTh/l: [H0|H1]^T split f16 [8192][1024]    2 x 4,194,304
// C0,C1: cell state fp32 [64000][64]         2 x 4,096,000
// Ah/Al: split f16 A [1024][1024]            2 x 524,288
// W0h/l: Wh0 split f16 [256][64]             2 x 8,192
// W1h/l: [Wx1|Wh1] split f16 [256][128]      2 x 16,384
// aliases: At fp32 (1M) in C0 region; Xr (6.14M) in AHh/AHl region.
#define WS_AX    0
#define WS_AHH   6144000
#define WS_AHL   10338304
#define WS_HTH   14532608
#define WS_HTL   18726912
#define WS_C0    22921216
#define WS_C1    27017216
#define WS_A16H  31113216
#define WS_A16L  31637504
#define WS_W0H   32161792
#define WS_W0L   32169984
#define WS_W1H   32178176
#define WS_W1L   32194560

// ---------------- A = softmax(relu(E1 @ E2^T)) in fp64, store A^T ----------------
__global__ __launch_bounds__(256) void compute_A(const float* __restrict__ E1,
                                                 const float* __restrict__ E2,
                                                 float* __restrict__ At)
{
    __shared__ double z[1000];
    __shared__ double red[256];
    __shared__ double e1[16];
    const int i = blockIdx.x;
    const int tid = threadIdx.x;
    if (tid < 16) e1[tid] = (double)E1[i * 16 + tid];
    __syncthreads();
    double lmax = -1e300;
    for (int j = tid; j < 1000; j += 256) {
        double s = 0.0;
        #pragma unroll
        for (int c = 0; c < 16; ++c) s += e1[c] * (double)E2[j * 16 + c];
        if (s < 0.0) s = 0.0;
        z[j] = s;
        if (s > lmax) lmax = s;
    }
    red[tid] = lmax; __syncthreads();
    for (int off = 128; off > 0; off >>= 1) {
        if (tid < off) red[tid] = fmax(red[tid], red[tid + off]);
        __syncthreads();
    }
    const double zmax = red[0];
    __syncthreads();
    double lsum = 0.0;
    for (int j = tid; j < 1000; j += 256) {
        double e = exp(z[j] - zmax);
        z[j] = e;
        lsum += e;
    }
    red[tid] = lsum; __syncthreads();
    for (int off = 128; off > 0; off >>= 1) {
        if (tid < off) red[tid] += red[tid + off];
        __syncthreads();
    }
    const double inv = 1.0 / red[0];
    for (int j = tid; j < 1000; j += 256)
        At[(size_t)j * 1000 + i] = (float)(z[j] * inv);
}

// ---------------- x [B,T,N,C] -> Xr [j][t*128 + b*2 + c] ----------------
__global__ __launch_bounds__(256) void transpose_x(const float* __restrict__ x,
                                                   float* __restrict__ Xr)
{
    int o = blockIdx.x * 256 + threadIdx.x;
    if (o >= 6144000) return;
    int j = o / 6144;
    int r = o - j * 6144;
    int t = r >> 7;
    int q = r & 127;
    int b = q >> 1;
    int c = q & 1;
    Xr[o] = x[(((size_t)(b * 48 + t)) * 1000 + j) * 2 + c];
}

__global__ __launch_bounds__(256) void zero_kernel(float* __restrict__ p, int n4)
{
    int i = blockIdx.x * 256 + threadIdx.x;
    if (i < n4) { f4 z = {0.f, 0.f, 0.f, 0.f}; ((f4*)p)[i] = z; }
}

// ---------------- weight split-f16 prep (once) ----------------
__global__ __launch_bounds__(256) void prep_w2(const float* __restrict__ Wh0,
                                               const float* __restrict__ Wx1,
                                               const float* __restrict__ Wh1,
                                               _Float16* __restrict__ W0h,
                                               _Float16* __restrict__ W0l,
                                               _Float16* __restrict__ W1h,
                                               _Float16* __restrict__ W1l)
{
    int idx = blockIdx.x * 256 + threadIdx.x;
    if (idx < 16384) {                    // [256 gc][64 k] = torch layout of Wh0
        float v = Wh0[idx];
        _Float16 hi = (_Float16)v;
        W0h[idx] = hi;
        W0l[idx] = (_Float16)((v - (float)hi) * 2048.f);
    }
    int j = idx - 16384;
    if (j >= 0 && j < 32768) {            // [256 gc][128 k]: k<64 -> Wx1, k>=64 -> Wh1
        int gc = j >> 7, k = j & 127;
        float v = (k < 64) ? Wx1[gc * 64 + k] : Wh1[gc * 64 + (k - 64)];
        _Float16 hi = (_Float16)v;
        W1h[j] = hi;
        W1l[j] = (_Float16)((v - (float)hi) * 2048.f);
    }
}

// ---------------- split A^T fp32 -> Ah/Al f16 [m=1024][k=1024] ----------------
__global__ __launch_bounds__(256) void prep_A(const float* __restrict__ At,
                                              _Float16* __restrict__ Ahh,
                                              _Float16* __restrict__ All)
{
    int idx = blockIdx.x * 256 + threadIdx.x;   // 1,048,576
    int m = idx >> 10, k = idx & 1023;
    float v = (m < 1000 && k < 1000) ? At[(size_t)k * 1000 + m] : 0.f;
    _Float16 hi = (_Float16)v;
    Ahh[idx] = hi;
    All[idx] = (_Float16)((v - (float)hi) * 2048.f);
}

// ---------------- fp32 GEMM (used once for AX) ----------------
__global__ __launch_bounds__(256) void gemm1000(const float* __restrict__ At,
                                                const float* __restrict__ B,
                                                float* __restrict__ C,
                                                int ncols)
{
    __shared__ float As[8][64];
    __shared__ float Bs[8][128];
    const int tid = threadIdx.x;
    const int tx = tid & 15;
    const int ty = tid >> 4;
    const int row0 = blockIdx.x * 64;
    const int col0 = blockIdx.y * 128;
    const int lm = tid & 63;
    const int lk = tid >> 6;
    const int bcol = tid & 127;
    const int bk = tid >> 7;
    const bool arow_ok = (row0 + lm) < 1000;

    float acc[4][8];
    #pragma unroll
    for (int r = 0; r < 4; ++r)
        #pragma unroll
        for (int c = 0; c < 8; ++c) acc[r][c] = 0.f;

    for (int k0 = 0; k0 < 1000; k0 += 8) {
        float a0 = arow_ok ? At[(size_t)(k0 + lk) * 1000 + row0 + lm] : 0.f;
        float a1 = arow_ok ? At[(size_t)(k0 + lk + 4) * 1000 + row0 + lm] : 0.f;
        float bv[4];
        #pragma unroll
        for (int kk = 0; kk < 4; ++kk)
            bv[kk] = B[(size_t)(k0 + bk * 4 + kk) * ncols + col0 + bcol];
        __syncthreads();
        As[lk][lm] = a0;
        As[lk + 4][lm] = a1;
        #pragma unroll
        for (int kk = 0; kk < 4; ++kk) Bs[bk * 4 + kk][bcol] = bv[kk];
        __syncthreads();
        #pragma unroll
        for (int k = 0; k < 8; ++k) {
            f4 av = *(const f4*)&As[k][ty * 4];
            f4 b0 = *(const f4*)&Bs[k][tx * 8];
            f4 b1 = *(const f4*)&Bs[k][tx * 8 + 4];
            #pragma unroll
            for (int r = 0; r < 4; ++r) {
                float a = av[r];
                acc[r][0] = fmaf(a, b0[0], acc[r][0]);
                acc[r][1] = fmaf(a, b0[1], acc[r][1]);
                acc[r][2] = fmaf(a, b0[2], acc[r][2]);
                acc[r][3] = fmaf(a, b0[3], acc[r][3]);
                acc[r][4] = fmaf(a, b1[0], acc[r][4]);
                acc[r][5] = fmaf(a, b1[1], acc[r][5]);
                acc[r][6] = fmaf(a, b1[2], acc[r][6]);
                acc[r][7] = fmaf(a, b1[3], acc[r][7]);
            }
        }
    }
    #pragma unroll
    for (int r = 0; r < 4; ++r) {
        int row = row0 + ty * 4 + r;
        if (row < 1000) {
            f4 o0 = {acc[r][0], acc[r][1], acc[r][2], acc[r][3]};
            f4 o1 = {acc[r][4], acc[r][5], acc[r][6], acc[r][7]};
            *(f4*)&C[(size_t)row * ncols + col0 + tx * 8]     = o0;
            *(f4*)&C[(size_t)row * ncols + col0 + tx * 8 + 4] = o1;
        }
    }
}

// ---------------- MFMA split-f16 GEMM: AH[1024][8192] = A @ HT^T (split-f16 out) ----------------
// BM=128 BN=128 BK=32; 256 thr = 4 waves 2x2; wave tile 64x64 = 4x4 frags 16x16x32.
// Grid 512 1D: m = id&7 (one m-panel per XCD), n = id>>3.
__global__ __launch_bounds__(256) void gemm_ah(
    const _Float16* __restrict__ Ahg, const _Float16* __restrict__ Alg,
    const _Float16* __restrict__ Bhg, const _Float16* __restrict__ Blg,
    _Float16* __restrict__ Ch, _Float16* __restrict__ Cl)
{
    __shared__ __align__(16) _Float16 Ahs[128 * 40];
    __shared__ __align__(16) _Float16 Als[128 * 40];
    __shared__ __align__(16) _Float16 Bhs[128 * 40];
    __shared__ __align__(16) _Float16 Bls[128 * 40];
    const int tid = threadIdx.x;
    const int lane = tid & 63;
    const int w = tid >> 6;
    const int wr = w >> 1, wc = w & 1;
    const int g = lane >> 4, l15 = lane & 15;
    const int m0 = (blockIdx.x & 7) * 128;
    const int n0 = (blockIdx.x >> 3) * 128;
    const int srow = tid >> 2;          // 0..63
    const int scol = (tid & 3) * 8;     // f16 col 0,8,16,24

    f4 acc0[4][4], acc1[4][4];
    #pragma unroll
    for (int a = 0; a < 4; ++a)
        #pragma unroll
        for (int b = 0; b < 4; ++b) {
            acc0[a][b] = (f4){0.f, 0.f, 0.f, 0.f};
            acc1[a][b] = (f4){0.f, 0.f, 0.f, 0.f};
        }

    for (int ks = 0; ks < 32; ++ks) {
        const int kb = ks * 32 + scol;
        f4 va[2], vl[2], vbh[2], vbl[2];
        #pragma unroll
        for (int s = 0; s < 2; ++s) {
            const size_t ga = (size_t)(m0 + s * 64 + srow) * 1024 + kb;
            const size_t gb = (size_t)(n0 + s * 64 + srow) * 1024 + kb;
            va[s]  = *(const f4*)&Ahg[ga];
            vl[s]  = *(const f4*)&Alg[ga];
            vbh[s] = *(const f4*)&Bhg[gb];
            vbl[s] = *(const f4*)&Blg[gb];
        }
        __syncthreads();
        #pragma unroll
        for (int s = 0; s < 2; ++s) {
            const int lo = (s * 64 + srow) * 40 + scol;
            *(f4*)&Ahs[lo] = va[s];
            *(f4*)&Als[lo] = vl[s];
            *(f4*)&Bhs[lo] = vbh[s];
            *(f4*)&Bls[lo] = vbl[s];
        }
        __syncthreads();

        h8 fa[4], fl[4];
        #pragma unroll
        for (int mf = 0; mf < 4; ++mf) {
            const int ao = (wr * 64 + mf * 16 + l15) * 40 + g * 8;
            fa[mf] = *(const h8*)&Ahs[ao];
            fl[mf] = *(const h8*)&Als[ao];
        }
        #pragma unroll
        for (int nf = 0; nf < 4; ++nf) {
            const int bo = (wc * 64 + nf * 16 + l15) * 40 + g * 8;
            const h8 bh = *(const h8*)&Bhs[bo];
            const h8 bl = *(const h8*)&Bls[bo];
            #pragma unroll
            for (int mf = 0; mf < 4; ++mf) {
                acc0[mf][nf] = __builtin_amdgcn_mfma_f32_16x16x32_f16(fa[mf], bh, acc0[mf][nf], 0, 0, 0);
                acc1[mf][nf] = __builtin_amdgcn_mfma_f32_16x16x32_f16(fa[mf], bl, acc1[mf][nf], 0, 0, 0);
                acc1[mf][nf] = __builtin_amdgcn_mfma_f32_16x16x32_f16(fl[mf], bh, acc1[mf][nf], 0, 0, 0);
            }
        }
    }

    // C/D layout (m89-verified): col = lane&15, row = (lane>>4)*4 + e; split-f16 out
    #pragma unroll
    for (int mf = 0; mf < 4; ++mf)
        #pragma unroll
        for (int nf = 0; nf < 4; ++nf) {
            const int row = m0 + wr * 64 + mf * 16 + g * 4;
            const int col = n0 + wc * 64 + nf * 16 + l15;
            #pragma unroll
            for (int e = 0; e < 4; ++e) {
                float v = acc0[mf][nf][e] + acc1[mf][nf][e] * (1.f / 2048.f);
                _Float16 hi = (_Float16)v;
                size_t o = (size_t)(row + e) * 8192 + col;
                Ch[o] = hi;
                Cl[o] = (_Float16)((v - (float)hi) * 2048.f);
            }
        }
}

// ---------------- LDS-staged MFMA gate GEMM + fused LSTM + fused HT write ----------------
// Block = (node-tile i0 of 64) x (one batch b). M=64 node rows, N=256 gc, K=64/128.
// gates[il][gc] = sum_k AH[i0+il][colbase+k] * W[gc][k]  (3-pass split-f16)
// Wave w owns h = w*16+l15 (gc = g*64+h, g=nf in-lane) -> LSTM pointwise fully in-lane.
// Epilogue writes HT[n=b*64+h][k=i] (k-contiguous per (n,mf): transpose fused, pad-k zeroed).
__global__ __launch_bounds__(256) void gates_hb(
    const _Float16* __restrict__ AHh, const _Float16* __restrict__ AHl,  // [1024][8192]
    int is_layer1,
    const _Float16* __restrict__ Wgh, const _Float16* __restrict__ Wgl,  // [256][K]
    const float* __restrict__ b1, const float* __restrict__ b2,
    const float* __restrict__ AX, const float* __restrict__ WxE, int t,  // layer0 x-path
    float* __restrict__ Cst,
    _Float16* __restrict__ HTh, _Float16* __restrict__ HTl, int nbase,   // 0 or 4096
    float* __restrict__ HF)                                              // fp32 H out (or null)
{
    __shared__ __align__(16) _Float16 Ahs[64 * 40];
    __shared__ __align__(16) _Float16 Als[64 * 40];
    __shared__ __align__(16) _Float16 Whs[256 * 40];
    __shared__ __align__(16) _Float16 Wls[256 * 40];
    const int tid = threadIdx.x;
    const int lane = tid & 63;
    const int w = tid >> 6;
    const int lg = lane >> 4, l15 = lane & 15;
    const int bb = blockIdx.x & 63;          // batch index
    const int i0 = (blockIdx.x >> 6) * 64;   // node tile
    const int K = is_layer1 ? 128 : 64;
    const int h = w * 16 + l15;
    const int arow = tid >> 2;               // 0..63
    const int acol = (tid & 3) * 8;          // 0,8,16,24

    f4 acc0[4][4], acc1[4][4];               // [mf][gate]
    #pragma unroll
    for (int a = 0; a < 4; ++a)
        #pragma unroll
        for (int b = 0; b < 4; ++b) {
            acc0[a][b] = (f4){0.f, 0.f, 0.f, 0.f};
            acc1[a][b] = (f4){0.f, 0.f, 0.f, 0.f};
        }

    const int nks = K >> 5;
    for (int ks = 0; ks < nks; ++ks) {
        const int colbase = ((ks < 2) ? 0 : 4096) + bb * 64 + (ks & 1) * 32;
        // reg prefetch: A chunk (1 h8 per buf), W chunk (4 h8 per buf)
        const size_t aad = (size_t)(i0 + arow) * 8192 + colbase + acol;
        h8 ra_h = *(const h8*)&AHh[aad];
        h8 ra_l = *(const h8*)&AHl[aad];
        h8 rw_h[4], rw_l[4];
        #pragma unroll
        for (int j = 0; j < 4; ++j) {
            const size_t wad = (size_t)tid * K + ks * 32 + j * 8;
            rw_h[j] = *(const h8*)&Wgh[wad];
            rw_l[j] = *(const h8*)&Wgl[wad];
        }
        __syncthreads();                     // previous chunk fully consumed
        *(h8*)&Ahs[arow * 40 + acol] = ra_h;
        *(h8*)&Als[arow * 40 + acol] = ra_l;
        #pragma unroll
        for (int j = 0; j < 4; ++j) {
            *(h8*)&Whs[tid * 40 + j * 8] = rw_h[j];
            *(h8*)&Wls[tid * 40 + j * 8] = rw_l[j];
        }
        __syncthreads();

        h8 fa[4], fl[4];
        #pragma unroll
        for (int mf = 0; mf < 4; ++mf) {
            const int ao = (mf * 16 + l15) * 40 + lg * 8;
            fa[mf] = *(const h8*)&Ahs[ao];
            fl[mf] = *(const h8*)&Als[ao];
        }
        #pragma unroll
        for (int nf = 0; nf < 4; ++nf) {     // nf = gate g
            const int bo = (nf * 64 + h) * 40 + lg * 8;
            const h8 bh = *(const h8*)&Whs[bo];
            const h8 bl = *(const h8*)&Wls[bo];
            #pragma unroll
            for (int mf = 0; mf < 4; ++mf) {
                acc0[mf][nf] = __builtin_amdgcn_mfma_f32_16x16x32_f16(fa[mf], bh, acc0[mf][nf], 0, 0, 0);
                acc1[mf][nf] = __builtin_amdgcn_mfma_f32_16x16x32_f16(fa[mf], bl, acc1[mf][nf], 0, 0, 0);
                acc1[mf][nf] = __builtin_amdgcn_mfma_f32_16x16x32_f16(fl[mf], bh, acc1[mf][nf], 0, 0, 0);
            }
        }
    }

    float bs[4], wx0[4], wx1v[4];
    #pragma unroll
    for (int g = 0; g < 4; ++g) {
        const int gc = g * 64 + h;
        bs[g] = b1[gc] + b2[gc];
        if (WxE) { wx0[g] = WxE[gc * 2]; wx1v[g] = WxE[gc * 2 + 1]; }
    }

    // C/D: col = gc (h fixed per lane), row il = mf*16 + lg*4 + e
    #pragma unroll
    for (int mf = 0; mf < 4; ++mf) {
        #pragma unroll
        for (int e = 0; e < 4; ++e) {
            const int il = mf * 16 + lg * 4 + e;
            const int i = i0 + il;
            const bool valid = (i < 1000);
            float hv = 0.f;
            if (valid) {
                float gv[4];
                #pragma unroll
                for (int g = 0; g < 4; ++g)
                    gv[g] = acc0[mf][g][e] + acc1[mf][g][e] * (1.f / 2048.f) + bs[g];
                if (AX) {
                    const float x0 = AX[(size_t)i * 6144 + t * 128 + bb * 2 + 0];
                    const float x1 = AX[(size_t)i * 6144 + t * 128 + bb * 2 + 1];
                    #pragma unroll
                    for (int g = 0; g < 4; ++g)
                        gv[g] = fmaf(x0, wx0[g], fmaf(x1, wx1v[g], gv[g]));
                }
                const float ig = 1.f / (1.f + expf(-gv[0]));
                const float fg = 1.f / (1.f + expf(-gv[1]));
                const float og = 1.f / (1.f + expf(-gv[2]));
                const float gg = tanhf(gv[3]);
                const size_t cb = (size_t)i * 4096 + bb * 64 + h;   // C[(i*64+b)][h]
                const float c = fg * Cst[cb] + ig * gg;
                Cst[cb] = c;
                hv = og * tanhf(c);
                if (HF) HF[cb] = hv;
            }
            const _Float16 hi = (_Float16)hv;
            const size_t ho = (size_t)(nbase + bb * 64 + h) * 1024 + i;
            HTh[ho] = hi;
            HTl[ho] = (_Float16)((hv - (float)hi) * 2048.f);
        }
    }
}

// ---------------- final projection (reads fp32 H1) ----------------
__global__ __launch_bounds__(256) void proj_kernel(const float* __restrict__ H1,
                                                   const float* __restrict__ Wpj,
                                                   const float* __restrict__ bp,
                                                   float* __restrict__ out)
{
    int r = blockIdx.x * 256 + threadIdx.x;
    if (r >= 64000) return;
    int i = r >> 6, b = r & 63;
    f4 hv[16];
    #pragma unroll
    for (int q = 0; q < 16; ++q) hv[q] = *(const f4*)&H1[(size_t)r * 64 + q * 4];
    #pragma unroll
    for (int hor = 0; hor < 12; ++hor) {
        float s = bp[hor];
        #pragma unroll
        for (int q = 0; q < 16; ++q) {
            f4 w = *(const f4*)&Wpj[hor * 64 + q * 4];
            s = fmaf(hv[q][0], w[0], s);
            s = fmaf(hv[q][1], w[1], s);
            s = fmaf(hv[q][2], w[2], s);
            s = fmaf(hv[q][3], w[3], s);
        }
        out[(size_t)(b * 12 + hor) * 1000 + i] = s;
    }
}

extern "C" void kernel_launch(void* const* d_in, const int* in_sizes, int n_in,
                              void* d_out, int out_size, void* d_ws, size_t ws_size,
                              hipStream_t stream)
{
    const float* x   = (const float*)d_in[0];
    const float* E1  = (const float*)d_in[1];
    const float* E2  = (const float*)d_in[2];
    const float* Wx0 = (const float*)d_in[3];
    const float* bx0 = (const float*)d_in[4];
    const float* Wh0 = (const float*)d_in[5];
    const float* bh0 = (const float*)d_in[6];
    const float* Wx1 = (const float*)d_in[7];
    const float* bx1 = (const float*)d_in[8];
    const float* Wh1 = (const float*)d_in[9];
    const float* bh1 = (const float*)d_in[10];
    const float* Wp  = (const float*)d_in[11];
    const float* bp  = (const float*)d_in[12];
    float* out = (float*)d_out;
    float* ws  = (float*)d_ws;

    float*    AX  = ws + WS_AX;
    _Float16* AHh = (_Float16*)(ws + WS_AHH);
    _Float16* AHl = (_Float16*)(ws + WS_AHL);
    _Float16* HTh = (_Float16*)(ws + WS_HTH);
    _Float16* HTl = (_Float16*)(ws + WS_HTL);
    float*    C0  = ws + WS_C0;
    float*    C1  = ws + WS_C1;
    _Float16* Ah  = (_Float16*)(ws + WS_A16H);
    _Float16* Al  = (_Float16*)(ws + WS_A16L);
    _Float16* W0h = (_Float16*)(ws + WS_W0H);
    _Float16* W0l = (_Float16*)(ws + WS_W0L);
    _Float16* W1h = (_Float16*)(ws + WS_W1H);
    _Float16* W1l = (_Float16*)(ws + WS_W1L);
    float*    At  = ws + WS_C0;     // alias: dead before C0/C1 zeroed
    float*    Xr  = ws + WS_AHH;    // alias: dead before AH/HT zeroed
    float*    H1F = ws + WS_AX;     // alias: written t=47 (AX dead), read by proj

    compute_A<<<1000, 256, 0, stream>>>(E1, E2, At);
    transpose_x<<<24000, 256, 0, stream>>>(x, Xr);
    gemm1000<<<dim3(16, 48), 256, 0, stream>>>(At, Xr, AX, 6144);    // AX = A @ Xr
    prep_w2<<<192, 256, 0, stream>>>(Wh0, Wx1, Wh1, W0h, W0l, W1h, W1l);
    prep_A<<<4096, 256, 0, stream>>>(At, Ah, Al);
    zero_kernel<<<8000, 256, 0, stream>>>(ws + WS_C0, 2048000);      // C0,C1 (kills At)
    zero_kernel<<<16384, 256, 0, stream>>>(ws + WS_AHH, 4194304);    // AHh,AHl,HTh,HTl (kills Xr)

    for (int t = 0; t < 48; ++t) {
        // layer 0: gates = (A@H0prev)Wh0^T + x-path -> C0, HT rows n<4096 (H0new^T)
        gates_hb<<<1024, 256, 0, stream>>>(AHh, AHl, 0, W0h, W0l, bh0, bx0,
                                           AX, Wx0, t, C0, HTh, HTl, 0, nullptr);
        // AH = A @ [H0new | H1prev]
        gemm_ah<<<512, 256, 0, stream>>>(Ah, Al, HTh, HTl, AHh, AHl);
        // layer 1: gates = (A@H0new)Wx1^T + (A@H1prev)Wh1^T -> C1, HT rows n>=4096
        gates_hb<<<1024, 256, 0, stream>>>(AHh, AHl, 1, W1h, W1l, bh1, bx1,
                                           nullptr, nullptr, 0, C1, HTh, HTl, 4096,
                                           (t == 47) ? H1F : nullptr);
    }
    proj_kernel<<<250, 256, 0, stream>>>(H1F, Wp, bp, out);
    (void)in_sizes; (void)n_in; (void)out_size; (void)ws_size;
}

// Round 7
// 9316.061 us; speedup vs baseline: 1.3061x; 1.3061x over previous
//
#include <hip/hip_runtime.h>
#include <math.h>

typedef float f4 __attribute__((ext_vector_type(4)));
typedef _Float16 h8 __attribute__((ext_vector_type(8)));

// ---------------- workspace layout (float offsets), end = 32,112,640 = 128.45 MB (== R4 proven) ----
// AX  : A@x all t [i][t*128+b*2+c]      6,144,000
// AHC : A@[H0|H1] fp32 [1024][8192]     8,388,608   (Xr alias, dead before zero)
// HF  : H fp32 [1000][4096] (=[r][64])  4,096,000   (shared H0/H1; H1 live at end)
// C0,C1: cell state fp32 [64000][64]    2 x 4,096,000   (At alias in C0, dead before zero)
// HTh/l: H^T split f16 [4096][1024]     2 x 2,097,152 (one layer at a time)
// Ah/Al: split f16 A [1024][1024]       2 x 524,288
// W0T [64][256], W1T [128][256] fp32
#define WS_AX    0
#define WS_AHC   6144000
#define WS_HF    14532608
#define WS_C0    18628608
#define WS_C1    22724608
#define WS_HTH   26820608
#define WS_HTL   28917760
#define WS_A16H  31014912
#define WS_A16L  31539200
#define WS_W0T   32063488
#define WS_W1T   32079872

// ---------------- A = softmax(relu(E1 @ E2^T)) in fp64, store A^T ----------------
__global__ __launch_bounds__(256) void compute_A(const float* __restrict__ E1,
                                                 const float* __restrict__ E2,
                                                 float* __restrict__ At)
{
    __shared__ double z[1000];
    __shared__ double red[256];
    __shared__ double e1[16];
    const int i = blockIdx.x;
    const int tid = threadIdx.x;
    if (tid < 16) e1[tid] = (double)E1[i * 16 + tid];
    __syncthreads();
    double lmax = -1e300;
    for (int j = tid; j < 1000; j += 256) {
        double s = 0.0;
        #pragma unroll
        for (int c = 0; c < 16; ++c) s += e1[c] * (double)E2[j * 16 + c];
        if (s < 0.0) s = 0.0;
        z[j] = s;
        if (s > lmax) lmax = s;
    }
    red[tid] = lmax; __syncthreads();
    for (int off = 128; off > 0; off >>= 1) {
        if (tid < off) red[tid] = fmax(red[tid], red[tid + off]);
        __syncthreads();
    }
    const double zmax = red[0];
    __syncthreads();
    double lsum = 0.0;
    for (int j = tid; j < 1000; j += 256) {
        double e = exp(z[j] - zmax);
        z[j] = e;
        lsum += e;
    }
    red[tid] = lsum; __syncthreads();
    for (int off = 128; off > 0; off >>= 1) {
        if (tid < off) red[tid] += red[tid + off];
        __syncthreads();
    }
    const double inv = 1.0 / red[0];
    for (int j = tid; j < 1000; j += 256)
        At[(size_t)j * 1000 + i] = (float)(z[j] * inv);
}

// ---------------- x [B,T,N,C] -> Xr [j][t*128 + b*2 + c] ----------------
__global__ __launch_bounds__(256) void transpose_x(const float* __restrict__ x,
                                                   float* __restrict__ Xr)
{
    int o = blockIdx.x * 256 + threadIdx.x;
    if (o >= 6144000) return;
    int j = o / 6144;
    int r = o - j * 6144;
    int t = r >> 7;
    int q = r & 127;
    int b = q >> 1;
    int c = q & 1;
    Xr[o] = x[(((size_t)(b * 48 + t)) * 1000 + j) * 2 + c];
}

__global__ __launch_bounds__(256) void zero_kernel(float* __restrict__ p, int n4)
{
    int i = blockIdx.x * 256 + threadIdx.x;
    if (i < n4) { f4 z = {0.f, 0.f, 0.f, 0.f}; ((f4*)p)[i] = z; }
}

// ---------------- weight transposes to [k][256] fp32 (once; R4-proven) ----------------
__global__ __launch_bounds__(256) void prep_w(const float* __restrict__ Wh0,
                                              const float* __restrict__ Wx1,
                                              const float* __restrict__ Wh1,
                                              float* __restrict__ W0T,
                                              float* __restrict__ W1T)
{
    int idx = blockIdx.x * 256 + threadIdx.x;
    if (idx < 16384) {
        int k = idx >> 8, o = idx & 255;
        W0T[idx] = Wh0[o * 64 + k];
    }
    int j = idx - 16384;
    if (j >= 0 && j < 32768) {
        int k = j >> 8, o = j & 255;
        W1T[j] = (k < 64) ? Wx1[o * 64 + k] : Wh1[o * 64 + (k - 64)];
    }
}

// ---------------- split A^T fp32 -> Ah/Al f16 [m=1024][k=1024] ----------------
__global__ __launch_bounds__(256) void prep_A(const float* __restrict__ At,
                                              _Float16* __restrict__ Ahh,
                                              _Float16* __restrict__ All)
{
    int idx = blockIdx.x * 256 + threadIdx.x;   // 1,048,576
    int m = idx >> 10, k = idx & 1023;
    float v = (m < 1000 && k < 1000) ? At[(size_t)k * 1000 + m] : 0.f;
    _Float16 hi = (_Float16)v;
    Ahh[idx] = hi;
    All[idx] = (_Float16)((v - (float)hi) * 2048.f);
}

// ---------------- fp32 GEMM (used once for AX; R1-proven) ----------------
__global__ __launch_bounds__(256) void gemm1000(const float* __restrict__ At,
                                                const float* __restrict__ B,
                                                float* __restrict__ C,
                                                int ncols)
{
    __shared__ float As[8][64];
    __shared__ float Bs[8][128];
    const int tid = threadIdx.x;
    const int tx = tid & 15;
    const int ty = tid >> 4;
    const int row0 = blockIdx.x * 64;
    const int col0 = blockIdx.y * 128;
    const int lm = tid & 63;
    const int lk = tid >> 6;
    const int bcol = tid & 127;
    const int bk = tid >> 7;
    const bool arow_ok = (row0 + lm) < 1000;

    float acc[4][8];
    #pragma unroll
    for (int r = 0; r < 4; ++r)
        #pragma unroll
        for (int c = 0; c < 8; ++c) acc[r][c] = 0.f;

    for (int k0 = 0; k0 < 1000; k0 += 8) {
        float a0 = arow_ok ? At[(size_t)(k0 + lk) * 1000 + row0 + lm] : 0.f;
        float a1 = arow_ok ? At[(size_t)(k0 + lk + 4) * 1000 + row0 + lm] : 0.f;
        float bv[4];
        #pragma unroll
        for (int kk = 0; kk < 4; ++kk)
            bv[kk] = B[(size_t)(k0 + bk * 4 + kk) * ncols + col0 + bcol];
        __syncthreads();
        As[lk][lm] = a0;
        As[lk + 4][lm] = a1;
        #pragma unroll
        for (int kk = 0; kk < 4; ++kk) Bs[bk * 4 + kk][bcol] = bv[kk];
        __syncthreads();
        #pragma unroll
        for (int k = 0; k < 8; ++k) {
            f4 av = *(const f4*)&As[k][ty * 4];
            f4 b0 = *(const f4*)&Bs[k][tx * 8];
            f4 b1 = *(const f4*)&Bs[k][tx * 8 + 4];
            #pragma unroll
            for (int r = 0; r < 4; ++r) {
                float a = av[r];
                acc[r][0] = fmaf(a, b0[0], acc[r][0]);
                acc[r][1] = fmaf(a, b0[1], acc[r][1]);
                acc[r][2] = fmaf(a, b0[2], acc[r][2]);
                acc[r][3] = fmaf(a, b0[3], acc[r][3]);
                acc[r][4] = fmaf(a, b1[0], acc[r][4]);
                acc[r][5] = fmaf(a, b1[1], acc[r][5]);
                acc[r][6] = fmaf(a, b1[2], acc[r][6]);
                acc[r][7] = fmaf(a, b1[3], acc[r][7]);
            }
        }
    }
    #pragma unroll
    for (int r = 0; r < 4; ++r) {
        int row = row0 + ty * 4 + r;
        if (row < 1000) {
            f4 o0 = {acc[r][0], acc[r][1], acc[r][2], acc[r][3]};
            f4 o1 = {acc[r][4], acc[r][5], acc[r][6], acc[r][7]};
            *(f4*)&C[(size_t)row * ncols + col0 + tx * 8]     = o0;
            *(f4*)&C[(size_t)row * ncols + col0 + tx * 8 + 4] = o1;
        }
    }
}

// ---------------- H fp32 [i][4096] -> HT split f16 [4096][1024] (R4-proven) ----------------
__global__ __launch_bounds__(256) void transpose_split(const float* __restrict__ H,
                                                       _Float16* __restrict__ HTh,
                                                       _Float16* __restrict__ HTl)
{
    __shared__ float tile[32][33];
    const int tid = threadIdx.x;
    const int tx = tid & 31;
    const int ty = tid >> 5;
    const int n0 = blockIdx.x * 32;
    const int k0 = blockIdx.y * 32;
    #pragma unroll
    for (int j = 0; j < 4; ++j) {
        int k = k0 + ty * 4 + j;
        tile[ty * 4 + j][tx] = (k < 1000) ? H[(size_t)k * 4096 + n0 + tx] : 0.f;
    }
    __syncthreads();
    #pragma unroll
    for (int j = 0; j < 4; ++j) {
        int n = n0 + ty * 4 + j;
        float v = tile[tx][ty * 4 + j];
        _Float16 hi = (_Float16)v;
        size_t o = (size_t)n * 1024 + k0 + tx;
        HTh[o] = hi;
        HTl[o] = (_Float16)((v - (float)hi) * 2048.f);
    }
}

// ---------------- MFMA split-f16 GEMM v2 (m97-style): AHC[:, coloff:coloff+4096] = A @ HT^T ----
// BM=64 BN=128 BK=32; 256 thr = 4 waves, wave tile 64x32 (4mf x 2nf frags 16x16x32).
// global_load_lds w16 -> linear LDS [row][4 slots of 8 f16]; XOR swizzle slot^=((row^(row>>2))&3)
// applied on BOTH the global source slot and the frag-read slot (involution).
// Grid 512: m = bid&15 (same XCD per m-panel: 16==0 mod 8), n = bid>>4.
#define GL16(srcp, dstoff) \
    __builtin_amdgcn_global_load_lds((const __attribute__((address_space(1))) unsigned int*)(srcp), \
        (__attribute__((address_space(3))) unsigned int*)(lds + (dstoff)), 16, 0, 0)

__device__ __forceinline__ int swzb(int row, int lg) {
    return row * 64 + ((lg ^ ((row ^ (row >> 2)) & 3)) << 4);
}

__global__ __launch_bounds__(256, 2) void gemm_ahv2(
    const _Float16* __restrict__ Ahg, const _Float16* __restrict__ Alg,
    const _Float16* __restrict__ Bhg, const _Float16* __restrict__ Blg,
    float* __restrict__ Cout, int coloff)
{
    // LDS: Ah [64][32] @0, Al @4096, Bh [128][32] @8192, Bl @16384  (24 KB)
    __shared__ __align__(1024) char lds[24576];
    const int tid = threadIdx.x;
    const int lane = tid & 63;
    const int w = tid >> 6;
    const int lg = lane >> 4, l15 = lane & 15;
    const int m0 = (blockIdx.x & 15) * 64;
    const int n0 = (blockIdx.x >> 4) * 128;

    // 6 staging chunks per wave; chunk c = w*6+q covers lds bytes [c*1024, c*1024+1024).
    // lane writes lds byte c*1024 + lane*16 -> (array-local) row = cl*16 + (lane>>2), slot = lane&3.
    const int r16 = lane >> 2;
    const int sd = lane & 3;
    const char* src[6];
    #pragma unroll
    for (int q = 0; q < 6; ++q) {
        const int c = w * 6 + q;
        int row;
        const _Float16* g;
        if (c < 4)       { row = (c)      * 16 + r16; g = Ahg + (size_t)(m0 + row) * 1024; }
        else if (c < 8)  { row = (c - 4)  * 16 + r16; g = Alg + (size_t)(m0 + row) * 1024; }
        else if (c < 16) { row = (c - 8)  * 16 + r16; g = Bhg + (size_t)(n0 + row) * 1024; }
        else             { row = (c - 16) * 16 + r16; g = Blg + (size_t)(n0 + row) * 1024; }
        const int cg = sd ^ ((row ^ (row >> 2)) & 3);   // global 8-f16 chunk for this lds slot
        src[q] = (const char*)(g + cg * 8);
    }

    f4 acc0[4][2], acc1[4][2];
    #pragma unroll
    for (int a = 0; a < 4; ++a)
        #pragma unroll
        for (int b = 0; b < 2; ++b) {
            acc0[a][b] = (f4){0.f, 0.f, 0.f, 0.f};
            acc1[a][b] = (f4){0.f, 0.f, 0.f, 0.f};
        }

    for (int ks = 0; ks < 32; ++ks) {
        const int kadv = ks * 64;                 // 32 f16 per K-step
        #pragma unroll
        for (int q = 0; q < 6; ++q)
            GL16(src[q] + kadv, (w * 6 + q) * 1024);
        __syncthreads();                          // drains vmcnt -> LDS data visible

        h8 fa[4], fl[4], bh[2], bl[2];
        #pragma unroll
        for (int mf = 0; mf < 4; ++mf) {
            const int ob = swzb(mf * 16 + l15, lg);
            fa[mf] = *(const h8*)(lds + ob);
            fl[mf] = *(const h8*)(lds + 4096 + ob);
        }
        #pragma unroll
        for (int nf = 0; nf < 2; ++nf) {
            const int ob = swzb(w * 32 + nf * 16 + l15, lg);
            bh[nf] = *(const h8*)(lds + 8192 + ob);
            bl[nf] = *(const h8*)(lds + 16384 + ob);
        }
        __syncthreads();                          // all reads done before next DMA overwrites

        #pragma unroll
        for (int nf = 0; nf < 2; ++nf)
            #pragma unroll
            for (int mf = 0; mf < 4; ++mf) {
                acc0[mf][nf] = __builtin_amdgcn_mfma_f32_16x16x32_f16(fa[mf], bh[nf], acc0[mf][nf], 0, 0, 0);
                acc1[mf][nf] = __builtin_amdgcn_mfma_f32_16x16x32_f16(fa[mf], bl[nf], acc1[mf][nf], 0, 0, 0);
                acc1[mf][nf] = __builtin_amdgcn_mfma_f32_16x16x32_f16(fl[mf], bh[nf], acc1[mf][nf], 0, 0, 0);
            }
    }

    // C/D (m89-verified): col = lane&15, row = (lane>>4)*4 + e
    #pragma unroll
    for (int mf = 0; mf < 4; ++mf)
        #pragma unroll
        for (int nf = 0; nf < 2; ++nf) {
            const int row = m0 + mf * 16 + lg * 4;
            const int col = coloff + n0 + w * 32 + nf * 16 + l15;
            #pragma unroll
            for (int e = 0; e < 4; ++e)
                Cout[(size_t)(row + e) * 8192 + col] =
                    acc0[mf][nf][e] + acc1[mf][nf][e] * (1.f / 2048.f);
        }
}

// ---------------- gate GEMM (R4-proven fp32) + LSTM pointwise; AHC row stride 8192 ----------------
// Block = node i (rows b=0..63), 256 gc. AH[b][k] = AHC[i*8192 + coff + b*64 + k].
__global__ __launch_bounds__(256) void gates_v2(
    const float* __restrict__ AH, int two,
    const float* __restrict__ WT,
    const float* __restrict__ b1, const float* __restrict__ b2,
    const float* __restrict__ AX, const float* __restrict__ WxE,
    int t,
    float* __restrict__ Cst, float* __restrict__ Hout)
{
    __shared__ float As[32][65];
    __shared__ float Bs[32 * 256];
    __shared__ float wx[512];
    const int tid = threadIdx.x;
    const int tx = tid & 15;
    const int ty = tid >> 4;
    const int bi = blockIdx.x;
    const int mrow = tid >> 3;          // 0..31
    const int f4i  = tid & 7;

    if (WxE && tid < 128) ((f4*)wx)[tid] = ((const f4*)WxE)[tid];

    f4 acc[4][4];
    #pragma unroll
    for (int r = 0; r < 4; ++r)
        #pragma unroll
        for (int gq = 0; gq < 4; ++gq) acc[r][gq] = (f4){0.f, 0.f, 0.f, 0.f};

    const size_t rowb = (size_t)bi * 8192;
    const int nchunk = two ? 4 : 2;
    for (int ch = 0; ch < nchunk; ++ch) {
        const int coff = (ch < 2) ? 0 : 4096;
        const int koff = (ch & 1) * 32;
        const float* srcb = AH + rowb + coff + koff;
        f4 av0 = *(const f4*)&srcb[(size_t)mrow * 64 + f4i * 4];
        f4 av1 = *(const f4*)&srcb[(size_t)(mrow + 32) * 64 + f4i * 4];
        const float* wsrc = WT + ch * 8192;
        f4 bv[8];
        #pragma unroll
        for (int r = 0; r < 8; ++r) bv[r] = *(const f4*)&wsrc[(tid + r * 256) * 4];
        __syncthreads();
        #pragma unroll
        for (int j = 0; j < 4; ++j) {
            As[f4i * 4 + j][mrow]      = av0[j];
            As[f4i * 4 + j][mrow + 32] = av1[j];
        }
        #pragma unroll
        for (int r = 0; r < 8; ++r) *(f4*)&Bs[(tid + r * 256) * 4] = bv[r];
        __syncthreads();
        #pragma unroll
        for (int k = 0; k < 32; ++k) {
            float a[4];
            #pragma unroll
            for (int rr = 0; rr < 4; ++rr) a[rr] = As[k][ty * 4 + rr];
            f4 bq[4];
            #pragma unroll
            for (int gq = 0; gq < 4; ++gq) bq[gq] = *(const f4*)&Bs[k * 256 + gq * 64 + tx * 4];
            #pragma unroll
            for (int rr = 0; rr < 4; ++rr)
                #pragma unroll
                for (int gq = 0; gq < 4; ++gq)
                    acc[rr][gq] += a[rr] * bq[gq];
        }
    }

    f4 bb[4];
    #pragma unroll
    for (int gq = 0; gq < 4; ++gq) {
        f4 v1 = *(const f4*)&b1[gq * 64 + tx * 4];
        f4 v2 = *(const f4*)&b2[gq * 64 + tx * 4];
        bb[gq] = v1 + v2;
    }

    #pragma unroll
    for (int rr = 0; rr < 4; ++rr) {
        const int b = ty * 4 + rr;
        const int r = bi * 64 + b;
        f4 gv[4];
        #pragma unroll
        for (int gq = 0; gq < 4; ++gq) gv[gq] = acc[rr][gq] + bb[gq];
        if (AX) {
            float x0 = AX[(size_t)bi * 6144 + t * 128 + b * 2 + 0];
            float x1 = AX[(size_t)bi * 6144 + t * 128 + b * 2 + 1];
            #pragma unroll
            for (int gq = 0; gq < 4; ++gq)
                #pragma unroll
                for (int hh = 0; hh < 4; ++hh) {
                    int gc = gq * 64 + tx * 4 + hh;
                    gv[gq][hh] = fmaf(x0, wx[gc * 2 + 0],
                                 fmaf(x1, wx[gc * 2 + 1], gv[gq][hh]));
                }
        }
        size_t base = (size_t)r * 64 + tx * 4;
        f4 cold = *(const f4*)&Cst[base];
        f4 cnew, hnew;
        #pragma unroll
        for (int hh = 0; hh < 4; ++hh) {
            float ig = 1.f / (1.f + expf(-gv[0][hh]));
            float fg = 1.f / (1.f + expf(-gv[1][hh]));
            float og = 1.f / (1.f + expf(-gv[2][hh]));
            float gg = tanhf(gv[3][hh]);
            float c  = fg * cold[hh] + ig * gg;
            cnew[hh] = c;
            hnew[hh] = og * tanhf(c);
        }
        *(f4*)&Cst[base]  = cnew;
        *(f4*)&Hout[base] = hnew;
    }
}

// ---------------- final projection (HF is [r][64]-dense; unchanged) ----------------
__global__ __launch_bounds__(256) void proj_kernel(const float* __restrict__ H1,
                                                   const float* __restrict__ Wpj,
                                                   const float* __restrict__ bp,
                                                   float* __restrict__ out)
{
    int r = blockIdx.x * 256 + threadIdx.x;
    if (r >= 64000) return;
    int i = r >> 6, b = r & 63;
    f4 hv[16];
    #pragma unroll
    for (int q = 0; q < 16; ++q) hv[q] = *(const f4*)&H1[(size_t)r * 64 + q * 4];
    #pragma unroll
    for (int hor = 0; hor < 12; ++hor) {
        float s = bp[hor];
        #pragma unroll
        for (int q = 0; q < 16; ++q) {
            f4 w = *(const f4*)&Wpj[hor * 64 + q * 4];
            s = fmaf(hv[q][0], w[0], s);
            s = fmaf(hv[q][1], w[1], s);
            s = fmaf(hv[q][2], w[2], s);
            s = fmaf(hv[q][3], w[3], s);
        }
        out[(size_t)(b * 12 + hor) * 1000 + i] = s;
    }
}

extern "C" void kernel_launch(void* const* d_in, const int* in_sizes, int n_in,
                              void* d_out, int out_size, void* d_ws, size_t ws_size,
                              hipStream_t stream)
{
    const float* x   = (const float*)d_in[0];
    const float* E1  = (const float*)d_in[1];
    const float* E2  = (const float*)d_in[2];
    const float* Wx0 = (const float*)d_in[3];
    const float* bx0 = (const float*)d_in[4];
    const float* Wh0 = (const float*)d_in[5];
    const float* bh0 = (const float*)d_in[6];
    const float* Wx1 = (const float*)d_in[7];
    const float* bx1 = (const float*)d_in[8];
    const float* Wh1 = (const float*)d_in[9];
    const float* bh1 = (const float*)d_in[10];
    const float* Wp  = (const float*)d_in[11];
    const float* bp  = (const float*)d_in[12];
    float* out = (float*)d_out;
    float* ws  = (float*)d_ws;

    float*    AX  = ws + WS_AX;
    float*    AHC = ws + WS_AHC;
    float*    HF  = ws + WS_HF;
    float*    C0  = ws + WS_C0;
    float*    C1  = ws + WS_C1;
    _Float16* HTh = (_Float16*)(ws + WS_HTH);
    _Float16* HTl = (_Float16*)(ws + WS_HTL);
    _Float16* Ah  = (_Float16*)(ws + WS_A16H);
    _Float16* Al  = (_Float16*)(ws + WS_A16L);
    float*    W0T = ws + WS_W0T;
    float*    W1T = ws + WS_W1T;
    float*    At  = ws + WS_C0;    // alias: dead before C0/C1 zeroed
    float*    Xr  = ws + WS_AHC;   // alias: dead before AHC zeroed

    compute_A<<<1000, 256, 0, stream>>>(E1, E2, At);
    transpose_x<<<24000, 256, 0, stream>>>(x, Xr);
    gemm1000<<<dim3(16, 48), 256, 0, stream>>>(At, Xr, AX, 6144);   // AX = A @ Xr
    prep_w<<<192, 256, 0, stream>>>(Wh0, Wx1, Wh1, W0T, W1T);
    prep_A<<<4096, 256, 0, stream>>>(At, Ah, Al);
    zero_kernel<<<8000, 256, 0, stream>>>(ws + WS_C0, 2048000);     // C0,C1 (kills At)
    zero_kernel<<<8192, 256, 0, stream>>>(AHC, 2097152);            // AHC (kills Xr)

    for (int t = 0; t < 48; ++t) {
        // layer 0: gates = (A@H0prev)[cols 0:4096] Wh0^T + x-path -> HF=H0new, C0
        gates_v2<<<1000, 256, 0, stream>>>(AHC, 0, W0T, bh0, bx0,
                                           AX, Wx0, t, C0, HF);
        transpose_split<<<dim3(128, 32), 256, 0, stream>>>(HF, HTh, HTl);
        gemm_ahv2<<<512, 256, 0, stream>>>(Ah, Al, HTh, HTl, AHC, 0);       // A@H0new
        // layer 1: gates = (A@H0new)Wx1^T + (A@H1prev)[cols 4096:] Wh1^T -> HF=H1new, C1
        gates_v2<<<1000, 256, 0, stream>>>(AHC, 1, W1T, bh1, bx1,
                                           nullptr, nullptr, 0, C1, HF);
        if (t < 47) {
            transpose_split<<<dim3(128, 32), 256, 0, stream>>>(HF, HTh, HTl);
            gemm_ahv2<<<512, 256, 0, stream>>>(Ah, Al, HTh, HTl, AHC, 4096); // A@H1new
        }
    }
    proj_kernel<<<250, 256, 0, stream>>>(HF, Wp, bp, out);
    (void)in_sizes; (void)n_in; (void)out_size; (void)ws_size;
}